// Round 2
// baseline (1205.346 us; speedup 1.0000x reference)
//
#include <hip/hip_runtime.h>
#include <hip/hip_fp16.h>
#include <stdint.h>

// ---------------------------------------------------------------------------
// SeqAE: enc LSTM (3->200, T=800, B=256) -> maxpool(T) -> dec LSTM (200->3)
// R2: 1 WG per batch, 832 threads (13 waves). 800 workers own ONE gate row
// each -> w[100] f16-pair VGPRs (fits 2048/13=157 budget; R1's 2-row/thread
// layout spilled: VGPR_Count=120 < 200 needed). Gate nonlinearities applied
// in the 800-wide phase. Decoder fused: 6-dim recurrence on lanes 0-2 with
// bitwise fixed-point early exit, coalesced cooperative writeback.
// ---------------------------------------------------------------------------

typedef _Float16 half2_t __attribute__((ext_vector_type(2)));

__device__ __forceinline__ float fdot2f(uint32_t hp, uint32_t wp, float acc) {
#if __has_builtin(__builtin_amdgcn_fdot2)
  return __builtin_amdgcn_fdot2(__builtin_bit_cast(half2_t, hp),
                                __builtin_bit_cast(half2_t, wp), acc, false);
#else
  half2_t a = __builtin_bit_cast(half2_t, hp);
  half2_t b = __builtin_bit_cast(half2_t, wp);
  return acc + (float)a[0] * (float)b[0] + (float)a[1] * (float)b[1];
#endif
}

__device__ __forceinline__ float hsig(float z) {
  return fminf(fmaxf(__builtin_fmaf(0.2f, z, 0.5f), 0.f), 1.f);
}

// tanh(x) = 1 - 2/(1+e^{2x});  e^{2x} = exp2(x * 2*log2(e))
__device__ __forceinline__ float tanh_fast(float v) {
  float e = __builtin_amdgcn_exp2f(v * 2.885390081777927f);
  return 1.f - 2.f * __builtin_amdgcn_rcpf(e + 1.f);
}

// --- pack Whh (800x200 f32, row-major) into f16 pairs, layout wpk[pair][row]
__global__ void prep_kernel(const float* __restrict__ whh,
                            uint32_t* __restrict__ wpk) {
  int idx = blockIdx.x * 256 + threadIdx.x;      // 100 pairs * 800 rows
  if (idx >= 80000) return;
  int p = idx / 800;
  int j = idx - p * 800;
  float a = whh[j * 200 + 2 * p];
  float b = whh[j * 200 + 2 * p + 1];
  __half2 v = __floats2half2_rn(a, b);
  wpk[idx] = __builtin_bit_cast(uint32_t, v);
}

// --- fused encoder + maxpool + decoder: grid 256 (batch), 832 threads
__global__ __launch_bounds__(832, 1)
void enc_kernel(const float* __restrict__ x,       // (256,3,800)
                const float* __restrict__ wih,     // (800,3)
                const float* __restrict__ bih,     // (800)
                const float* __restrict__ bhh,     // (800)
                const uint32_t* __restrict__ wpk,  // (100,800) f16 pairs
                const float* __restrict__ dwih,    // (12,200)
                const float* __restrict__ dbih,    // (12)
                const float* __restrict__ dbhh,    // (12)
                const float* __restrict__ dwhh,    // (12,3)
                float* __restrict__ out)           // (256,3,800)
{
  const int b = blockIdx.x;
  const int t = threadIdx.x;

  __shared__ float xs[2400];              // x staging; reused as dec hist[3][800]
  __shared__ alignas(16) __half hh[200];  // h_{t-1} as f16 pairs
  __shared__ float gates[800];            // ACTIVATED gate values
  __shared__ float pooled[200];
  __shared__ float pre12s[12];
  __shared__ int s_tc;

  for (int i = t; i < 2400; i += 832) xs[i] = x[(size_t)b * 2400 + i];
  if (t < 200) hh[t] = __float2half(0.f);

  const bool worker = t < 800;
  const int gtype = t / 200;              // 0=i 1=f 2=g 3=o
  uint32_t w[100];
  float bias = 0.f, wi0 = 0.f, wi1 = 0.f, wi2 = 0.f;
  if (worker) {
#pragma unroll
    for (int p = 0; p < 100; ++p) w[p] = wpk[p * 800 + t];   // coalesced
    bias = bih[t] + bhh[t];
    wi0 = wih[t * 3 + 0]; wi1 = wih[t * 3 + 1]; wi2 = wih[t * 3 + 2];
  }
  float c_state = 0.f;
  float maxh = -INFINITY;
  __syncthreads();

  for (int step = 0; step < 800; ++step) {
    if (worker) {
      float a0 = 0.f, a1 = 0.f;
      const uint4* H4 = (const uint4*)hh;
#pragma unroll
      for (int q = 0; q < 25; ++q) {
        uint4 Hv = H4[q];                 // broadcast read: 4 h-pairs
        a0 = fdot2f(Hv.x, w[4 * q + 0], a0);
        a1 = fdot2f(Hv.y, w[4 * q + 1], a1);
        a0 = fdot2f(Hv.z, w[4 * q + 2], a0);
        a1 = fdot2f(Hv.w, w[4 * q + 3], a1);
      }
      float g = a0 + a1 + bias;
      g = __builtin_fmaf(wi0, xs[step], g);
      g = __builtin_fmaf(wi1, xs[800 + step], g);
      g = __builtin_fmaf(wi2, xs[1600 + step], g);
      // apply nonlinearity here, in the 800-wide phase (divergent only in
      // the two waves straddling the t=400/600 boundaries... t=200*k edges)
      float act;
      if (gtype == 2) act = tanh_fast(g); else act = hsig(g);
      gates[t] = act;
    }
    __syncthreads();
    if (t < 200) {
      float ai = gates[t], af = gates[t + 200];
      float ag = gates[t + 400], ao = gates[t + 600];
      c_state = __builtin_fmaf(af, c_state, ai * ag);
      float h_ = ao * tanh_fast(c_state);
      maxh = fmaxf(maxh, h_);
      hh[t] = __float2half(h_);
    }
    __syncthreads();
  }

  // ---- maxpool result -> decoder constant input pre12 ----
  if (t < 200) pooled[t] = maxh;
  __syncthreads();
  if (t < 12) {
    float s = dbih[t] + dbhh[t];
    const float* wr = dwih + t * 200;
#pragma unroll 8
    for (int u = 0; u < 200; ++u) s = __builtin_fmaf(pooled[u], wr[u], s);
    pre12s[t] = s;
  }
  __syncthreads();

  // ---- decoder: lanes 0..2 run the 6-dim recurrence redundantly (lockstep),
  //      each writes its own feature column into hist = xs[f*800 + step].
  //      Bitwise fixed-point early exit.
  if (t < 3) {
    float pre[12];
#pragma unroll
    for (int j = 0; j < 12; ++j) pre[j] = pre12s[j];
    float W[36];
#pragma unroll
    for (int j = 0; j < 36; ++j) W[j] = dwhh[j];

    float h0 = 0, h1 = 0, h2 = 0, c0 = 0, c1 = 0, c2 = 0;
    int tc = 800;
    float* hist = xs + t * 800;
    for (int step = 0; step < 800; ++step) {
      float g[12];
#pragma unroll
      for (int j = 0; j < 12; ++j) {
        float v = pre[j];
        v = __builtin_fmaf(W[j * 3 + 0], h0, v);
        v = __builtin_fmaf(W[j * 3 + 1], h1, v);
        v = __builtin_fmaf(W[j * 3 + 2], h2, v);
        g[j] = v;
      }
      float nc0 = hsig(g[3]) * c0 + hsig(g[0]) * tanh_fast(g[6]);
      float nc1 = hsig(g[4]) * c1 + hsig(g[1]) * tanh_fast(g[7]);
      float nc2 = hsig(g[5]) * c2 + hsig(g[2]) * tanh_fast(g[8]);
      float nh0 = hsig(g[9])  * tanh_fast(nc0);
      float nh1 = hsig(g[10]) * tanh_fast(nc1);
      float nh2 = hsig(g[11]) * tanh_fast(nc2);
      bool same = (nh0 == h0) && (nh1 == h1) && (nh2 == h2) &&
                  (nc0 == c0) && (nc1 == c1) && (nc2 == c2);
      float mine = (t == 0) ? nh0 : ((t == 1) ? nh1 : nh2);
      hist[step] = mine;
      h0 = nh0; h1 = nh1; h2 = nh2; c0 = nc0; c1 = nc1; c2 = nc2;
      if (same) { tc = step + 1; break; }   // exact fixed point
    }
    if (t == 0) s_tc = tc;
  }
  __syncthreads();

  // ---- coalesced writeback: out[b, f, tt] = hist[f][min(tt, tc-1)] ----
  {
    const int tc1 = s_tc - 1;
    float* ob = out + (size_t)b * 2400;
    if (t < 800) {
      int idx = (t < s_tc) ? t : tc1;
      ob[t]        = xs[idx];
      ob[800 + t]  = xs[800 + idx];
      ob[1600 + t] = xs[1600 + idx];
    }
  }
}

extern "C" void kernel_launch(void* const* d_in, const int* in_sizes, int n_in,
                              void* d_out, int out_size, void* d_ws, size_t ws_size,
                              hipStream_t stream)
{
  const float* x    = (const float*)d_in[0];
  const float* wih  = (const float*)d_in[1];
  const float* whh  = (const float*)d_in[2];
  const float* bih  = (const float*)d_in[3];
  const float* bhh  = (const float*)d_in[4];
  const float* dwih = (const float*)d_in[5];
  const float* dwhh = (const float*)d_in[6];
  const float* dbih = (const float*)d_in[7];
  const float* dbhh = (const float*)d_in[8];
  float* out = (float*)d_out;

  uint32_t* wpk = (uint32_t*)d_ws;   // 320000 B

  hipLaunchKernelGGL(prep_kernel, dim3(313), dim3(256), 0, stream, whh, wpk);
  hipLaunchKernelGGL(enc_kernel, dim3(256), dim3(832), 0, stream,
                     x, wih, bih, bhh, wpk, dwih, dbih, dbhh, dwhh, out);
}